// Round 27
// baseline (237.910 us; speedup 1.0000x reference)
//
#include <hip/hip_runtime.h>
#include <hip/hip_bf16.h>
#include <cmath>

#define T_TOK 8192
#define DMODEL 1024
#define NHEAD 8
#define DH 128
#define NEXP 8
#define NNE 64      // NHEAD*NEXP
#define DHID 512

typedef __bf16 bf16x8 __attribute__((ext_vector_type(8)));
typedef float f32x4 __attribute__((ext_vector_type(4)));
typedef unsigned short u16x8 __attribute__((ext_vector_type(8)));

#define GLDS16(g, l) __builtin_amdgcn_global_load_lds( \
    (const __attribute__((address_space(1))) unsigned int*)(g), \
    (__attribute__((address_space(3))) unsigned int*)(l), 16, 0, 0)

static __device__ inline unsigned short f2bf(float f) {
  return __builtin_bit_cast(unsigned short, __float2bfloat16(f));
}
static __device__ inline float bf2f(unsigned short u) {
  unsigned int v = ((unsigned int)u) << 16;
  return __builtin_bit_cast(float, v);
}

// exact-accuracy fast gelu: Abramowitz-Stegun 7.1.26 erf (|eps|<=1.5e-7)
static __device__ inline float gelu_f(float v) {
  const float u = v * 0.70710678118654752f;
  const float s = fabsf(u);
  const float t = __builtin_amdgcn_rcpf(fmaf(0.3275911f, s, 1.0f));
  const float e = __expf(-s * s);
  float p = fmaf(1.061405429f, t, -1.453152027f);
  p = fmaf(p, t, 1.421413741f);
  p = fmaf(p, t, -0.284496736f);
  p = fmaf(p, t, 0.254829592f);
  p = p * t;
  const float erfs = fmaf(-p, e, 1.0f);
  const float erfv = copysignf(erfs, u);
  return 0.5f * v * (1.0f + erfv);
}

// ---------------- K0: reff head — Rtp[k/2][ne][2] fp64 + lb + counts zero ----------------
// 32 blocks x 256 thr: block = (n, 4 j-slices via 4 waves).
__global__ __launch_bounds__(256) void reff_kernel(
    const float* __restrict__ in_w, const float* __restrict__ in_b,
    const float* __restrict__ router_w, double* __restrict__ Rtp,
    double* __restrict__ lb, int* __restrict__ counts)
{
  __shared__ double rw[8][DH];   // 8 KB
  const int rbid = blockIdx.x;
  const int tid = threadIdx.x;
  if (rbid == 0 && tid < NNE) counts[tid] = 0;   // replaces memset launch
  const int n  = rbid >> 2;
  const int w  = tid >> 6;
  const int lane = tid & 63;
  const int js = ((rbid & 3) << 2) + w;       // 0..15
  const int j = js*64 + lane;
  for (int i = tid; i < 8*DH; i += 256)
    rw[i >> 7][i & 127] = (double)router_w[(size_t)(n*8 + (i >> 7))*DH + (i & 127)];
  __syncthreads();
  double acc[8];
  #pragma unroll
  for (int e = 0; e < 8; ++e) acc[e] = 0.0;
  const float* wp = in_w + (size_t)(n*DH)*DMODEL + j;
  #pragma unroll 8
  for (int d = 0; d < DH; ++d) {
    const double wv = (double)wp[(size_t)d*DMODEL];
    #pragma unroll
    for (int e = 0; e < 8; ++e) acc[e] += wv * rw[e][d];
  }
  #pragma unroll
  for (int e = 0; e < 8; ++e)
    Rtp[(size_t)(j >> 1)*128 + (n*8 + e)*2 + (j & 1)] = acc[e];
  if (js == 0 && lane < 8) {
    double a = 0.0;
    for (int d = 0; d < DH; ++d) a += (double)in_b[n*DH + d] * rw[lane][d];
    lb[n*8 + lane] = a;
  }
}

// ---------------- P0: merged prep + router partials ----------------
// blocks [0,64): w_out transpose (ne = bid)
// blocks [64,960): fp32->bf16 convert of {x, in_w, out_w, w_in}, grid-stride
// blocks [960,5056): router partials — ONE wave-task per block, decode from
//   blockIdx ONLY (workgroup-uniform -> x reads stay s_load; rounds 16/21
//   proved tid-derived decode demotes them to per-lane VMEM). Threads >=64
//   exit immediately (no barrier in this branch).
__global__ __launch_bounds__(256) void prep_router_kernel(
    const float* __restrict__ x, const float* __restrict__ in_w,
    const float* __restrict__ out_w, const float* __restrict__ w_in,
    const float* __restrict__ wout_src,
    unsigned short* __restrict__ x_bf, unsigned short* __restrict__ inw_bf,
    unsigned short* __restrict__ outw_bf, unsigned short* __restrict__ win_bf,
    unsigned short* __restrict__ woutT,
    const double* __restrict__ Rtp, double* __restrict__ part)
{
  __shared__ __align__(16) float ws[32][DH+4];   // transpose scratch
  const int bid = blockIdx.x;
  const int tid = threadIdx.x;

  if (bid < NNE) {
    // ---- w_out [ne][f][d] fp32 -> woutT [ne][d][f] bf16 ----
    const int ne = bid;
    const float* src = wout_src + (size_t)ne*DHID*DH;
    unsigned short* dst = woutT + (size_t)ne*DH*DHID;
    for (int fc = 0; fc < DHID; fc += 32) {
      __syncthreads();
      for (int i = tid; i < 32*DH; i += 256) {
        const int f = i >> 7, d = i & 127;
        ws[f][d] = src[(size_t)(fc+f)*DH + d];
      }
      __syncthreads();
      for (int i = tid; i < 32*DH; i += 256) {
        const int d = i >> 5, f = i & 31;
        dst[(size_t)d*DHID + fc + f] = f2bf(ws[f][d]);
      }
    }
  } else if (bid < 960) {
    // ---- fp32 -> bf16 convert, grid-stride over 4 buffers ----
    const int N0 = T_TOK*DMODEL/8;
    const int N1 = N0 + DMODEL*DMODEL/8;
    const int N2 = N1 + DMODEL*DMODEL/8;
    const int N3 = N2 + NNE*DHID*DH/8;
    const int nblk = 960 - 64;
    for (int i = (bid - 64)*256 + tid; i < N3; i += nblk*256) {
      const float* s; unsigned short* d; int o;
      if (i < N0)      { s = x;     d = x_bf;    o = i; }
      else if (i < N1) { s = in_w;  d = inw_bf;  o = i - N0; }
      else if (i < N2) { s = out_w; d = outw_bf; o = i - N1; }
      else             { s = w_in;  d = win_bf;  o = i - N2; }
      const float4 a = *((const float4*)s + (size_t)o*2);
      const float4 b = *((const float4*)s + (size_t)o*2 + 1);
      u16x8 v;
      v[0]=f2bf(a.x); v[1]=f2bf(a.y); v[2]=f2bf(a.z); v[3]=f2bf(a.w);
      v[4]=f2bf(b.x); v[5]=f2bf(b.y); v[6]=f2bf(b.z); v[7]=f2bf(b.w);
      *((u16x8*)d + o) = v;
    }
  } else {
    // ---- fp64 router partial: ONE wave active, blockIdx-only decode ----
    if (tid >= 64) return;                 // idle waves exit (no barriers here)
    const int rb = bid - 960;              // 0..4095
    const int s  = rb & 3;
    const int tg = rb >> 2;
    const int t0 = tg << 3;
    const int k0 = s << 8;
    const int lane = tid;                  // ne

    double acc[8];
    #pragma unroll
    for (int t = 0; t < 8; ++t) acc[t] = 0.0;

    const float*  xb = x + (size_t)t0*DMODEL + k0;
    const double* rb2 = Rtp + (size_t)(k0 >> 1)*128 + lane*2;

    #pragma unroll 2
    for (int kc = 0; kc < 256; kc += 8) {
      const double* r = rb2 + (size_t)(kc >> 1)*128;
      const double2 r0 = *(const double2*)(r);
      const double2 r1 = *(const double2*)(r + 128);
      const double2 r2 = *(const double2*)(r + 256);
      const double2 r3 = *(const double2*)(r + 384);
      #pragma unroll
      for (int t = 0; t < 8; ++t) {
        const float4 xa = *(const float4*)(xb + (size_t)t*DMODEL + kc);
        const float4 xc = *(const float4*)(xb + (size_t)t*DMODEL + kc + 4);
        acc[t] += (double)xa.x * r0.x;
        acc[t] += (double)xa.y * r0.y;
        acc[t] += (double)xa.z * r1.x;
        acc[t] += (double)xa.w * r1.y;
        acc[t] += (double)xc.x * r2.x;
        acc[t] += (double)xc.y * r2.y;
        acc[t] += (double)xc.z * r3.x;
        acc[t] += (double)xc.w * r3.y;
      }
    }
    #pragma unroll
    for (int t = 0; t < 8; ++t)
      part[((size_t)s*T_TOK + t0 + t)*NNE + lane] = acc[t];
  }
}

// ---------------- K2: gemm1 (blocks 0..511) + top-2 scatter (blocks 512..767) ----------------
__global__ __launch_bounds__(256) void gemm1_top2(
    const unsigned short* __restrict__ A, const unsigned short* __restrict__ B,
    const float* __restrict__ bias, unsigned short* __restrict__ C,
    const double* __restrict__ part, const double* __restrict__ lb,
    int* __restrict__ counts, int* __restrict__ lists, float* __restrict__ wbuf)
{
  const int bid = blockIdx.x;
  const int t = threadIdx.x;

  if (bid < 512) {
    const int N = DMODEL, K = DMODEL;
    __shared__ __align__(16) unsigned short As[128*64];   // 16 KB
    __shared__ __align__(16) unsigned short Bs[128*64];   // 16 KB
    const int lane = t & 63, w = t >> 6;
    const int bm = (bid & 63) << 7, bn = (bid >> 6) << 7;
    const int wm = (w & 1) << 6, wn = (w >> 1) << 6;
    f32x4 acc[4][4];
    #pragma unroll
    for (int i = 0; i < 4; ++i)
      #pragma unroll
      for (int j = 0; j < 4; ++j)
        acc[i][j] = (f32x4){0.f, 0.f, 0.f, 0.f};

    const int srow = t >> 3;                        // 0..31
    const int scol = ((t & 7) ^ (srow & 7)) << 3;   // inverse-swizzled source col
    const unsigned short* gA = A + (size_t)(bm + srow)*K + scol;
    const unsigned short* gB = B + (size_t)(bn + srow)*K + scol;
    const size_t row32 = (size_t)32*K;
    char* lA = (char*)As + t*16;
    char* lB = (char*)Bs + t*16;
    const int rlo = lane & 15;
    const int khi = (lane >> 4) << 4;

    int aRd[4][2], bRd[4][2];
    #pragma unroll
    for (int i = 0; i < 4; ++i) {
      const int ra = wm + i*16 + rlo;
      const int rb2 = wn + i*16 + rlo;
      #pragma unroll
      for (int ks = 0; ks < 2; ++ks) {
        aRd[i][ks] = ra*128 + ((ks*64 + khi) ^ ((ra & 7) << 4));
        bRd[i][ks] = rb2*128 + ((ks*64 + khi) ^ ((rb2 & 7) << 4));
      }
    }

    for (int k0 = 0; k0 < K; k0 += 64) {
      GLDS16(gA + k0,            lA);
      GLDS16(gA + row32 + k0,    lA + 4096);
      GLDS16(gA + 2*row32 + k0,  lA + 8192);
      GLDS16(gA + 3*row32 + k0,  lA + 12288);
      GLDS16(gB + k0,            lB);
      GLDS16(gB + row32 + k0,    lB + 4096);
      GLDS16(gB + 2*row32 + k0,  lB + 8192);
      GLDS16(gB + 3*row32 + k0,  lB + 12288);
      __syncthreads();
      #pragma unroll
      for (int ks = 0; ks < 2; ++ks) {
        bf16x8 av[4], bv[4];
        #pragma unroll
        for (int i = 0; i < 4; ++i) {
          av[i] = *(const bf16x8*)((const char*)As + aRd[i][ks]);
          bv[i] = *(const bf16x8*)((const char*)Bs + bRd[i][ks]);
        }
        #pragma unroll
        for (int i = 0; i < 4; ++i)
          #pragma unroll
          for (int j = 0; j < 4; ++j)
            acc[i][j] = __builtin_amdgcn_mfma_f32_16x16x32_bf16(av[i], bv[j], acc[i][j], 0, 0, 0);
      }
      __syncthreads();
    }
    const int rq = (lane >> 4) << 2;
    #pragma unroll
    for (int j = 0; j < 4; ++j) {
      const int col = bn + wn + j*16 + rlo;
      const float bb = bias[col];
      #pragma unroll
      for (int i = 0; i < 4; ++i) {
        const int row0 = bm + wm + i*16 + rq;
        #pragma unroll
        for (int r = 0; r < 4; ++r)
          C[(size_t)(row0 + r)*N + col] = f2bf(acc[i][j][r] + bb);
      }
    }
  } else {
    // ---- top-2 + softmax + hierarchical bucket scatter ----
    __shared__ int lcnt[NNE];
    __shared__ int lbase[NNE];
    const int u = (bid - 512)*256 + t;   // (tok, head)
    const int tok = u >> 3;
    const int head = u & 7;
    if (t < NNE) lcnt[t] = 0;
    __syncthreads();

    const size_t base = (size_t)tok*NNE + head*8;
    double l[NEXP];
    #pragma unroll
    for (int e = 0; e < NEXP; e += 2) {
      double2 p0 = *(const double2*)(part + base + e);
      double2 p1 = *(const double2*)(part + (size_t)T_TOK*NNE   + base + e);
      double2 p2 = *(const double2*)(part + (size_t)2*T_TOK*NNE + base + e);
      double2 p3 = *(const double2*)(part + (size_t)3*T_TOK*NNE + base + e);
      l[e]   = (((p0.x + p1.x) + p2.x) + p3.x) + lb[head*8 + e];
      l[e+1] = (((p0.y + p1.y) + p2.y) + p3.y) + lb[head*8 + e + 1];
    }
    int e1 = 0; double v1 = l[0];
    #pragma unroll
    for (int e = 1; e < NEXP; ++e) if (l[e] > v1) { v1 = l[e]; e1 = e; }
    int e2 = -1; double v2 = -1.0e300;
    #pragma unroll
    for (int e = 0; e < NEXP; ++e) if (e != e1 && l[e] > v2) { v2 = l[e]; e2 = e; }
    const double ed = exp(v2 - v1);
    const float w1 = (float)(1.0 / (1.0 + ed));
    const float w2 = (float)(ed / (1.0 + ed));
    const int b1 = head*NEXP + e1, b2 = head*NEXP + e2;

    wbuf[(size_t)(tok*NHEAD + head)*2 + 0] = w1;
    wbuf[(size_t)(tok*NHEAD + head)*2 + 1] = w2;

    const int p1i = atomicAdd(&lcnt[b1], 1);
    const int p2i = atomicAdd(&lcnt[b2], 1);
    __syncthreads();
    if (t < NNE) lbase[t] = atomicAdd(&counts[t], lcnt[t]);
    __syncthreads();
    lists[(size_t)b1*T_TOK + lbase[b1] + p1i] = tok*2;
    lists[(size_t)b2*T_TOK + lbase[b2] + p2i] = tok*2 + 1;
  }
}

// ---------------- out GEMM: BK=64 swizzled; bm-keyed XCD; slot-fusion in A ----------------
__global__ __launch_bounds__(256) void gemm_out(
    const unsigned short* __restrict__ ye, const unsigned short* __restrict__ B,
    const float* __restrict__ bias, float* __restrict__ C)
{
  const int N = DMODEL, K = DMODEL;
  __shared__ __align__(16) unsigned short As[128*64];   // 16 KB
  __shared__ __align__(16) unsigned short Bs[128*64];   // 16 KB
  const int t = threadIdx.x;
  const int lane = t & 63, w = t >> 6;
  const int bm = blockIdx.x << 7, bn = blockIdx.y << 7;
  const int wm = (w & 1) << 6, wn = (w >> 1) << 6;
  f32x4 acc[4][4];
  #pragma unroll
  for (int i = 0; i < 4; ++i)
    #pragma unroll
    for (int j = 0; j < 4; ++j)
      acc[i][j] = (f32x4){0.f, 0.f, 0.f, 0.f};

  const int srow = t >> 3;
  const int scol = ((t & 7) ^ (srow & 7)) << 3;
  const unsigned short* gB = B + (size_t)(bn + srow)*K + scol;
  const size_t row32 = (size_t)32*K;
  char* lB = (char*)Bs + t*16;
  const int arow = t >> 1;            // 0..127
  const int ah   = (t & 1) << 5;      // element offset 0/32 within 64-k step
  const int rlo = lane & 15;
  const int khi = (lane >> 4) << 4;

  int aRd[4][2], bRd[4][2];
  #pragma unroll
  for (int i = 0; i < 4; ++i) {
    const int ra = wm + i*16 + rlo;
    const int rb2 = wn + i*16 + rlo;
    #pragma unroll
    for (int ks = 0; ks < 2; ++ks) {
      aRd[i][ks] = ra*128 + ((ks*64 + khi) ^ ((ra & 7) << 4));
      bRd[i][ks] = rb2*128 + ((ks*64 + khi) ^ ((rb2 & 7) << 4));
    }
  }
  int aWr[4];
  #pragma unroll
  for (int j = 0; j < 4; ++j)
    aWr[j] = arow*128 + (((ah + 8*j)*2) ^ ((arow & 7) << 4));

  for (int k0 = 0; k0 < K; k0 += 64) {
    GLDS16(gB + k0,            lB);
    GLDS16(gB + row32 + k0,    lB + 4096);
    GLDS16(gB + 2*row32 + k0,  lB + 8192);
    GLDS16(gB + 3*row32 + k0,  lB + 12288);
    {
      const int head = k0 >> 7;
      const int inHead = (k0 & 127) + ah;
      const unsigned short* r0 = ye + (((size_t)(bm + arow)*NHEAD + head)*2)*DH + inHead;
      const unsigned short* r1 = r0 + DH;
      #pragma unroll
      for (int j = 0; j < 4; ++j) {
        const u16x8 a = *(const u16x8*)(r0 + 8*j);
        const u16x8 b = *(const u16x8*)(r1 + 8*j);
        u16x8 s;
        #pragma unroll
        for (int q = 0; q < 8; ++q) s[q] = f2bf(bf2f(a[q]) + bf2f(b[q]));
        *(u16x8*)((char*)As + aWr[j]) = s;
      }
    }
    __syncthreads();
    #pragma unroll
    for (int ks = 0; ks < 2; ++ks) {
      bf16x8 av[4], bv[4];
      #pragma unroll
      for (int i = 0; i < 4; ++i) {
        av[i] = *(const bf16x8*)((const char*)As + aRd[i][ks]);
        bv[i] = *(const bf16x8*)((const char*)Bs + bRd[i][ks]);
      }
      #pragma unroll
      for (int i = 0; i < 4; ++i)
        #pragma unroll
        for (int j = 0; j < 4; ++j)
          acc[i][j] = __builtin_amdgcn_mfma_f32_16x16x32_bf16(av[i], bv[j], acc[i][j], 0, 0, 0);
    }
    __syncthreads();
  }
  const int rq = (lane >> 4) << 2;
  #pragma unroll
  for (int j = 0; j < 4; ++j) {
    const int col = bn + wn + j*16 + rlo;
    const float bb = bias[col];
    #pragma unroll
    for (int i = 0; i < 4; ++i) {
      const int row0 = bm + wm + i*16 + rq;
      #pragma unroll
      for (int r = 0; r < 4; ++r)
        C[(size_t)(row0 + r)*N + col] = acc[i][j][r] + bb;
    }
  }
}

// ---------------- K3: fused expert FFN — dbuf weights via hA-space reuse ----------------
// (thrice-confirmed round-20/22/24 version: 80KB LDS, VGPR 60, no spill)
__global__ __launch_bounds__(512, 4) void ffn_mfma_kernel(
    const unsigned short* __restrict__ h_bf, const unsigned short* __restrict__ win_bf,
    const unsigned short* __restrict__ woutT_bf, const int* __restrict__ counts,
    const int* __restrict__ lists, const float* __restrict__ wbuf,
    unsigned short* __restrict__ ye_buf)
{
  const int ne = blockIdx.x;
  const int n  = ne >> 3;
  const int cnt = counts[ne];
  const int t0 = blockIdx.y << 7;
  if (t0 >= cnt) return;
  const int nt = min(128, cnt - t0);

  __shared__ __align__(16) unsigned short lds[40960];   // 80 KB
  char* const L = (char*)lds;

  const int t = threadIdx.x;
  const int lane = t & 63, w = t >> 6;
  const long lbase = (long)ne * T_TOK;

  // gather token rows of h into hA region [48K,80K)
  #pragma unroll
  for (int s = 0; s < 4; ++s) {
    const int o = s*8192 + t*16;
    const int row = o >> 8;
    const int c = (t & 15) ^ (row & 7);
    const int trow = t0 + row;
    const int ts = lists[lbase + (trow < cnt ? trow : t0)];
    const unsigned short* g = h_bf + (size_t)(ts >> 1)*DMODEL + n*DH + c*8;
    GLDS16(g, L + 49152 + o);
  }

  const unsigned short* winB  = win_bf  + (size_t)ne*DHID*DH;
  const unsigned short* woutB = woutT_bf + (size_t)ne*DH*DHID;

  const int wm = (w & 3) << 5;
  const int wf = (w >> 2) << 5;
  const int wd = (w >> 2) << 6;
  const int rlo = lane & 15;
  const int kq  = lane >> 4;

  int aAddr[2][4];
  #pragma unroll
  for (int i = 0; i < 2; ++i) {
    const int tr = wm + i*16 + rlo;
    #pragma unroll
    for (int ks = 0; ks < 4; ++ks)
      aAddr[i][ks] = tr*256 + ((ks*64 + kq*16) ^ ((tr & 7) << 4));
  }
  int bAddr[2][4];
  #pragma unroll
  for (int j = 0; j < 2; ++j) {
    const int fr = wf + j*16 + rlo;
    #pragma unroll
    for (int ks = 0; ks < 4; ++ks)
      bAddr[j][ks] = fr*256 + ((ks*64 + kq*16) ^ ((fr & 7) << 4));
  }
  int hWAddr[2][2];
  #pragma unroll
  for (int j = 0; j < 2; ++j)
    #pragma unroll
    for (int i = 0; i < 2; ++i) {
      const int tcol = wm + i*16 + rlo;
      const int fb   = wf + j*16 + kq*4;
      hWAddr[j][i] = tcol*128 + ((fb*2) ^ ((tcol & 7) << 4));
    }
  int a2Addr[2][2];
  #pragma unroll
  for (int i = 0; i < 2; ++i) {
    const int tr = wm + i*16 + rlo;
    #pragma unroll
    for (int ks = 0; ks < 2; ++ks)
      a2Addr[i][ks] = tr*128 + ((ks*64 + kq*16) ^ ((tr & 7) << 4));
  }
  int b2Addr[4][2];
  #pragma unroll
  for (int j = 0; j < 4; ++j) {
    const int dr = wd + j*16 + rlo;
    #pragma unroll
    for (int ks = 0; ks < 2; ++ks)
      b2Addr[j][ks] = dr*128 + ((ks*64 + kq*16) ^ ((dr & 7) << 4));
  }

  // pb = 0 (buf0) or 32768 (buf1)
  auto stage_win = [&](int fc, int pb) {
    #pragma unroll
    for (int s = 0; s < 2; ++s) {
      const int o = s*8192 + t*16;
      const int row = o >> 8;
      const int c = (t & 15) ^ (row & 7);
      GLDS16(winB + (size_t)(fc + row)*DH + c*8, L + 16384 + pb + o);
    }
  };
  auto stage_wout = [&](int fc, int pb) {
    #pragma unroll
    for (int s = 0; s < 2; ++s) {
      const int o = s*8192 + t*16;
      const int row = o >> 7;
      const int c = (t & 7) ^ (row & 7);
      GLDS16(woutB + (size_t)row*DHID + fc + c*8, L + 32768 + pb + o);
    }
  };

  f32x4 acc2[4][2];
  #pragma unroll
  for (int j = 0; j < 4; ++j)
    #pragma unroll
    for (int i = 0; i < 2; ++i)
      acc2[j][i] = (f32x4){0.f, 0.f, 0.f, 0.f};

  // prologue: hA + buf0 staged; cache ALL A-fragments; free hA space
  stage_win(0, 0);
  stage_wout(0, 0);
  __syncthreads();               // hA + buf0 visible
  bf16x8 aReg[2][4];
  #pragma unroll
  for (int i = 0; i < 2; ++i)
    #pragma unroll
    for (int ks = 0; ks < 4; ++ks)
      aReg[i][ks] = *(const bf16x8*)(L + 49152 + aAddr[i][ks]);
  __syncthreads();               // aReg reads complete -> hA space reusable

  #pragma unroll 1
  for (int c = 0; c < DHID/64; ++c) {
    const int fc = c << 6;
    const int pb = (c & 1) << 15;          // current buf: 0 / 32768
    if (c + 1 < DHID/64) {                 // stage next chunk into other buf
      const int qb = pb ^ 32768;
      stage_win(fc + 64, qb);
      stage_wout(fc + 64, qb);
    }
    // GEMM1: pure regs (A) + wIn[pb]
    f32x4 acc1[2][2];
    #pragma unroll
    for (int j = 0; j < 2; ++j)
      #pragma unroll
      for (int i = 0; i < 2; ++i)
        acc1[j][i] = (f32x4){0.f,0.f,0.f,0.f};
    __builtin_amdgcn_s_setprio(1);
    #pragma unroll
    for (int ks = 0; ks < 4; ++ks) {
      bf16x8 b[2];
      #pragma unroll
      for (int j = 0; j < 2; ++j)
        b[j] = *(const bf16x8*)(L + 16384 + pb + bAddr[j][ks]);
      #pragma unroll
      for (int j = 0; j < 2; ++j)
        #pragma unroll
        for (int i = 0; i < 2; ++i)
          acc1[j][i] = __builtin_amdgcn_mfma_f32_16x16x32_bf16(b[j], aReg[i][ks], acc1[j][i], 0, 0, 0);
    }
    __builtin_amdgcn_s_setprio(0);
    // gelu + packed b64 hid writes
    #pragma unroll
    for (int j = 0; j < 2; ++j)
      #pragma unroll
      for (int i = 0; i < 2; ++i) {
        const float g0 = gelu_f(acc1[j][i][0]);
        const float g1 = gelu_f(acc1[j][i][1]);
        const float g2 = gelu_f(acc1[j][i][2]);
        const float g3 = gelu_f(acc1[j][i][3]);
        const unsigned int lo = (unsigned int)f2bf(g0) | ((unsigned int)f2bf(g1) << 16);
        const unsigned int hi = (unsigned int)f2bf(g2) | ((unsigned int)f2bf(g3) << 16);
        *(uint2*)(L + hWAddr[j][i]) = make_uint2(lo, hi);
      }
    __syncthreads();   // BAR 1: staging(c+1) landed + hid visible (cover = GEMM1+gelu)

    // GEMM2: hidS + wOut[pb]
    __builtin_amdgcn_s_setprio(1);
    #pragma unroll
    for (int ks = 0; ks < 2; ++ks) {
      bf16x8 a[2], b[4];
      #pragma unroll
      for (int i = 0; i < 2; ++i)
        a[i] = *(const bf16x8*)(L + a2Addr[i][ks]);
      #pragma unroll
      for (int j = 0; j < 4; ++j)
        b[j] = *(const bf16x8*)(L + 32768 + pb + b2Addr[j][ks]);
      #pragma unroll
      for (int j = 0; j < 4; ++j)
        #pragma unroll
        for (int i = 0; i < 2; ++i)
          acc2[j][i] = __builtin_amdgcn_mfma_f32_16x16x32_bf16(b[j], a[i], acc2[j][i], 0, 0, 0);
    }
    __builtin_amdgcn_s_setprio(0);
    __syncthreads();   // BAR 2: hidS reads done -> next gelu may overwrite
  }

  // epilogue: gate-premultiplied packed b64 stores; lane holds 4 consecutive d
  #pragma unroll
  for (int i = 0; i < 2; ++i) {
    const int tr = wm + i*16 + rlo;
    if (tr < nt) {
      const int ts = lists[lbase + t0 + tr];
      const float gw = wbuf[(size_t)(ts >> 1)*NHEAD*2 + n*2 + (ts & 1)];
      unsigned short* dst = ye_buf +
          ((((size_t)(ts >> 1))*NHEAD + n)*2 + (ts & 1))*DH + wd + kq*4;
      #pragma unroll
      for (int j = 0; j < 4; ++j) {
        const unsigned int lo = (unsigned int)f2bf(gw*acc2[j][i][0]) |
                                ((unsigned int)f2bf(gw*acc2[j][i][1]) << 16);
        const unsigned int hi = (unsigned int)f2bf(gw*acc2[j][i][2]) |
                                ((unsigned int)f2bf(gw*acc2[j][i][3]) << 16);
        *(uint2*)(dst + j*16) = make_uint2(lo, hi);
      }
    }
  }
}

// ---------------- launch ----------------
extern "C" void kernel_launch(void* const* d_in, const int* in_sizes, int n_in,
                              void* d_out, int out_size, void* d_ws, size_t ws_size,
                              hipStream_t stream) {
  const float* x        = (const float*)d_in[0];
  const float* in_w     = (const float*)d_in[1];
  const float* in_b     = (const float*)d_in[2];
  const float* router_w = (const float*)d_in[3];
  const float* w_in     = (const float*)d_in[4];
  const float* w_out    = (const float*)d_in[5];
  const float* out_w    = (const float*)d_in[6];
  const float* out_b    = (const float*)d_in[7];
  float* out = (float*)d_out;

  size_t off = 0;
  char* base = (char*)d_ws;
  auto alloc = [&](size_t bytes) -> void* {
    void* p = base + off;
    off += (bytes + 255) & ~(size_t)255;
    return p;
  };
  unsigned short* h_bf    = (unsigned short*)alloc((size_t)T_TOK*DMODEL*2);
  unsigned short* x_bf    = (unsigned short*)alloc((size_t)T_TOK*DMODEL*2);
  unsigned short* inw_bf  = (unsigned short*)alloc((size_t)DMODEL*DMODEL*2);
  unsigned short* outw_bf = (unsigned short*)alloc((size_t)DMODEL*DMODEL*2);
  unsigned short* win_bf  = (unsigned short*)alloc((size_t)NNE*DHID*DH*2);
  unsigned short* woutT_bf= (unsigned short*)alloc((size_t)NNE*DH*DHID*2);
  unsigned short* ye_buf  = (unsigned short*)alloc((size_t)T_TOK*NHEAD*2*DH*2);
  float*  wbuf   = (float*) alloc((size_t)T_TOK*NHEAD*2*4);
  double* Rtp    = (double*)alloc((size_t)DMODEL*NNE*8);
  double* lb     = (double*)alloc(NNE*8);
  int*    counts = (int*)   alloc(NNE*4);
  int*    lists  = (int*)   alloc((size_t)NNE*T_TOK*4);
  double* part   = (double*)ye_buf;   // aliases ye_buf (router done before ffn)

  // reff head: Rtp + lb + counts zeroing
  reff_kernel<<<32, 256, 0, stream>>>(in_w, in_b, router_w, Rtp, lb, counts);

  // merged prep (transpose | cvt) + router partials (blockIdx-only decode)
  prep_router_kernel<<<5056, 256, 0, stream>>>(x, in_w, out_w, w_in, w_out,
                                               x_bf, inw_bf, outw_bf, win_bf,
                                               woutT_bf, Rtp, part);

  // gemm1 (h = x @ in_w^T + in_b, bf16) + top-2 scatter, merged
  gemm1_top2<<<768, 256, 0, stream>>>(x_bf, inw_bf, in_b, h_bf,
                                      part, lb, counts, lists, wbuf);

  // expert FFN (top-2 sparse), dbuf weights
  ffn_mfma_kernel<<<dim3(NNE, T_TOK/128), 512, 0, stream>>>(
      h_bf, win_bf, woutT_bf, counts, lists, wbuf, ye_buf);

  // out = (ye0 + ye1) @ out_w^T + out_b  (fp32 out, BK=64 swizzled, bm-keyed XCD)
  gemm_out<<<dim3(T_TOK/128, DMODEL/128), 256, 0, stream>>>(
      ye_buf, outw_bf, out_b, out);
}

// Round 28
// 219.768 us; speedup vs baseline: 1.0826x; 1.0826x over previous
//
#include <hip/hip_runtime.h>
#include <hip/hip_bf16.h>
#include <cmath>

#define T_TOK 8192
#define DMODEL 1024
#define NHEAD 8
#define DH 128
#define NEXP 8
#define NNE 64      // NHEAD*NEXP
#define DHID 512

typedef __bf16 bf16x8 __attribute__((ext_vector_type(8)));
typedef float f32x4 __attribute__((ext_vector_type(4)));
typedef unsigned short u16x8 __attribute__((ext_vector_type(8)));

#define GLDS16(g, l) __builtin_amdgcn_global_load_lds( \
    (const __attribute__((address_space(1))) unsigned int*)(g), \
    (__attribute__((address_space(3))) unsigned int*)(l), 16, 0, 0)

static __device__ inline unsigned short f2bf(float f) {
  return __builtin_bit_cast(unsigned short, __float2bfloat16(f));
}
static __device__ inline float bf2f(unsigned short u) {
  unsigned int v = ((unsigned int)u) << 16;
  return __builtin_bit_cast(float, v);
}

// exact-accuracy fast gelu: Abramowitz-Stegun 7.1.26 erf (|eps|<=1.5e-7)
static __device__ inline float gelu_f(float v) {
  const float u = v * 0.70710678118654752f;
  const float s = fabsf(u);
  const float t = __builtin_amdgcn_rcpf(fmaf(0.3275911f, s, 1.0f));
  const float e = __expf(-s * s);
  float p = fmaf(1.061405429f, t, -1.453152027f);
  p = fmaf(p, t, 1.421413741f);
  p = fmaf(p, t, -0.284496736f);
  p = fmaf(p, t, 0.254829592f);
  p = p * t;
  const float erfs = fmaf(-p, e, 1.0f);
  const float erfv = copysignf(erfs, u);
  return 0.5f * v * (1.0f + erfv);
}

// ---------------- P0: merged prep ----------------
// blocks [0,64): w_out transpose (ne = bid)
// blocks [64,96): reff — block = (n, 4 j-slices via 4 waves)
// blocks [96,992): fp32->bf16 convert of {x, in_w, out_w, w_in}, grid-stride
__global__ __launch_bounds__(256) void prep_kernel(
    const float* __restrict__ x, const float* __restrict__ in_w,
    const float* __restrict__ out_w, const float* __restrict__ w_in,
    const float* __restrict__ wout_src, const float* __restrict__ in_b,
    const float* __restrict__ router_w,
    unsigned short* __restrict__ x_bf, unsigned short* __restrict__ inw_bf,
    unsigned short* __restrict__ outw_bf, unsigned short* __restrict__ win_bf,
    unsigned short* __restrict__ woutT, double* __restrict__ Rtp, double* __restrict__ lb)
{
  __shared__ __align__(16) char smem[17408];
  const int bid = blockIdx.x;
  const int tid = threadIdx.x;

  if (bid < NNE) {
    // ---- w_out [ne][f][d] fp32 -> woutT [ne][d][f] bf16 ----
    float (*ws)[DH+4] = (float(*)[DH+4])smem;
    const int ne = bid;
    const float* src = wout_src + (size_t)ne*DHID*DH;
    unsigned short* dst = woutT + (size_t)ne*DH*DHID;
    for (int fc = 0; fc < DHID; fc += 32) {
      __syncthreads();
      for (int i = tid; i < 32*DH; i += 256) {
        const int f = i >> 7, d = i & 127;
        ws[f][d] = src[(size_t)(fc+f)*DH + d];
      }
      __syncthreads();
      for (int i = tid; i < 32*DH; i += 256) {
        const int d = i >> 5, f = i & 31;
        dst[(size_t)d*DHID + fc + f] = f2bf(ws[f][d]);
      }
    }
  } else if (bid < NNE + 32) {
    // ---- reff: Rtp[k/2][ne][2] fp64 ----
    double (*rw)[DH] = (double(*)[DH])smem;
    const int rbid = bid - NNE;
    const int n  = rbid >> 2;
    const int w  = tid >> 6;
    const int lane = tid & 63;
    const int js = ((rbid & 3) << 2) + w;       // 0..15
    const int j = js*64 + lane;
    for (int i = tid; i < 8*DH; i += 256)
      rw[i >> 7][i & 127] = (double)router_w[(size_t)(n*8 + (i >> 7))*DH + (i & 127)];
    __syncthreads();
    double acc[8];
    #pragma unroll
    for (int e = 0; e < 8; ++e) acc[e] = 0.0;
    const float* wp = in_w + (size_t)(n*DH)*DMODEL + j;
    #pragma unroll 8
    for (int d = 0; d < DH; ++d) {
      const double wv = (double)wp[(size_t)d*DMODEL];
      #pragma unroll
      for (int e = 0; e < 8; ++e) acc[e] += wv * rw[e][d];
    }
    #pragma unroll
    for (int e = 0; e < 8; ++e)
      Rtp[(size_t)(j >> 1)*128 + (n*8 + e)*2 + (j & 1)] = acc[e];
    if (js == 0 && lane < 8) {
      double a = 0.0;
      for (int d = 0; d < DH; ++d) a += (double)in_b[n*DH + d] * rw[lane][d];
      lb[n*8 + lane] = a;
    }
  } else {
    // ---- fp32 -> bf16 convert, grid-stride over 4 buffers ----
    const int N0 = T_TOK*DMODEL/8;
    const int N1 = N0 + DMODEL*DMODEL/8;
    const int N2 = N1 + DMODEL*DMODEL/8;
    const int N3 = N2 + NNE*DHID*DH/8;
    const int nblk = 992 - 96;
    for (int i = (bid - 96)*256 + tid; i < N3; i += nblk*256) {
      const float* s; unsigned short* d; int o;
      if (i < N0)      { s = x;     d = x_bf;    o = i; }
      else if (i < N1) { s = in_w;  d = inw_bf;  o = i - N0; }
      else if (i < N2) { s = out_w; d = outw_bf; o = i - N1; }
      else             { s = w_in;  d = win_bf;  o = i - N2; }
      const float4 a = *((const float4*)s + (size_t)o*2);
      const float4 b = *((const float4*)s + (size_t)o*2 + 1);
      u16x8 v;
      v[0]=f2bf(a.x); v[1]=f2bf(a.y); v[2]=f2bf(a.z); v[3]=f2bf(a.w);
      v[4]=f2bf(b.x); v[5]=f2bf(b.y); v[6]=f2bf(b.z); v[7]=f2bf(b.w);
      *((u16x8*)d + o) = v;
    }
  }
}

// ---------------- K1a: fp64 partial logits (block-uniform x -> s_load) ----------------
__global__ __launch_bounds__(64) void router_partial(
    const float* __restrict__ x, const double* __restrict__ Rtp,
    double* __restrict__ part)
{
  const int bid = blockIdx.x;
  const int s  = bid & 3;
  const int tg = bid >> 2;
  const int t0 = tg << 3;
  const int k0 = s << 8;
  const int lane = threadIdx.x;          // ne

  double acc[8];
  #pragma unroll
  for (int t = 0; t < 8; ++t) acc[t] = 0.0;

  const float*  xb = x + (size_t)t0*DMODEL + k0;
  const double* rb = Rtp + (size_t)(k0 >> 1)*128 + lane*2;

  #pragma unroll 2
  for (int kc = 0; kc < 256; kc += 8) {
    const double* r = rb + (size_t)(kc >> 1)*128;
    const double2 r0 = *(const double2*)(r);
    const double2 r1 = *(const double2*)(r + 128);
    const double2 r2 = *(const double2*)(r + 256);
    const double2 r3 = *(const double2*)(r + 384);
    #pragma unroll
    for (int t = 0; t < 8; ++t) {
      const float4 xa = *(const float4*)(xb + (size_t)t*DMODEL + kc);
      const float4 xc = *(const float4*)(xb + (size_t)t*DMODEL + kc + 4);
      acc[t] += (double)xa.x * r0.x;
      acc[t] += (double)xa.y * r0.y;
      acc[t] += (double)xa.z * r1.x;
      acc[t] += (double)xa.w * r1.y;
      acc[t] += (double)xc.x * r2.x;
      acc[t] += (double)xc.y * r2.y;
      acc[t] += (double)xc.z * r3.x;
      acc[t] += (double)xc.w * r3.y;
    }
  }
  #pragma unroll
  for (int t = 0; t < 8; ++t)
    part[((size_t)s*T_TOK + t0 + t)*NNE + lane] = acc[t];
}

// ---------------- K2: gemm1 (blocks 0..511) + top-2 scatter (blocks 512..767) ----------------
// gemm branch dominates the VGPR union (top2 ~40 VGPR) -> gemm occupancy
// unaffected. bm = bid&63 keeps XCD = bm%8 (A-panel L2 locality).
__global__ __launch_bounds__(256) void gemm1_top2(
    const unsigned short* __restrict__ A, const unsigned short* __restrict__ B,
    const float* __restrict__ bias, unsigned short* __restrict__ C,
    const double* __restrict__ part, const double* __restrict__ lb,
    int* __restrict__ counts, int* __restrict__ lists, float* __restrict__ wbuf)
{
  const int bid = blockIdx.x;
  const int t = threadIdx.x;

  if (bid < 512) {
    const int N = DMODEL, K = DMODEL;
    __shared__ __align__(16) unsigned short As[128*64];   // 16 KB
    __shared__ __align__(16) unsigned short Bs[128*64];   // 16 KB
    const int lane = t & 63, w = t >> 6;
    const int bm = (bid & 63) << 7, bn = (bid >> 6) << 7;
    const int wm = (w & 1) << 6, wn = (w >> 1) << 6;
    f32x4 acc[4][4];
    #pragma unroll
    for (int i = 0; i < 4; ++i)
      #pragma unroll
      for (int j = 0; j < 4; ++j)
        acc[i][j] = (f32x4){0.f, 0.f, 0.f, 0.f};

    const int srow = t >> 3;                        // 0..31
    const int scol = ((t & 7) ^ (srow & 7)) << 3;   // inverse-swizzled source col
    const unsigned short* gA = A + (size_t)(bm + srow)*K + scol;
    const unsigned short* gB = B + (size_t)(bn + srow)*K + scol;
    const size_t row32 = (size_t)32*K;
    char* lA = (char*)As + t*16;
    char* lB = (char*)Bs + t*16;
    const int rlo = lane & 15;
    const int khi = (lane >> 4) << 4;

    int aRd[4][2], bRd[4][2];
    #pragma unroll
    for (int i = 0; i < 4; ++i) {
      const int ra = wm + i*16 + rlo;
      const int rb2 = wn + i*16 + rlo;
      #pragma unroll
      for (int ks = 0; ks < 2; ++ks) {
        aRd[i][ks] = ra*128 + ((ks*64 + khi) ^ ((ra & 7) << 4));
        bRd[i][ks] = rb2*128 + ((ks*64 + khi) ^ ((rb2 & 7) << 4));
      }
    }

    for (int k0 = 0; k0 < K; k0 += 64) {
      GLDS16(gA + k0,            lA);
      GLDS16(gA + row32 + k0,    lA + 4096);
      GLDS16(gA + 2*row32 + k0,  lA + 8192);
      GLDS16(gA + 3*row32 + k0,  lA + 12288);
      GLDS16(gB + k0,            lB);
      GLDS16(gB + row32 + k0,    lB + 4096);
      GLDS16(gB + 2*row32 + k0,  lB + 8192);
      GLDS16(gB + 3*row32 + k0,  lB + 12288);
      __syncthreads();
      #pragma unroll
      for (int ks = 0; ks < 2; ++ks) {
        bf16x8 av[4], bv[4];
        #pragma unroll
        for (int i = 0; i < 4; ++i) {
          av[i] = *(const bf16x8*)((const char*)As + aRd[i][ks]);
          bv[i] = *(const bf16x8*)((const char*)Bs + bRd[i][ks]);
        }
        #pragma unroll
        for (int i = 0; i < 4; ++i)
          #pragma unroll
          for (int j = 0; j < 4; ++j)
            acc[i][j] = __builtin_amdgcn_mfma_f32_16x16x32_bf16(av[i], bv[j], acc[i][j], 0, 0, 0);
      }
      __syncthreads();
    }
    const int rq = (lane >> 4) << 2;
    #pragma unroll
    for (int j = 0; j < 4; ++j) {
      const int col = bn + wn + j*16 + rlo;
      const float bb = bias[col];
      #pragma unroll
      for (int i = 0; i < 4; ++i) {
        const int row0 = bm + wm + i*16 + rq;
        #pragma unroll
        for (int r = 0; r < 4; ++r)
          C[(size_t)(row0 + r)*N + col] = f2bf(acc[i][j][r] + bb);
      }
    }
  } else {
    // ---- top-2 + softmax + hierarchical bucket scatter ----
    __shared__ int lcnt[NNE];
    __shared__ int lbase[NNE];
    const int u = (bid - 512)*256 + t;   // (tok, head)
    const int tok = u >> 3;
    const int head = u & 7;
    if (t < NNE) lcnt[t] = 0;
    __syncthreads();

    const size_t base = (size_t)tok*NNE + head*8;
    double l[NEXP];
    #pragma unroll
    for (int e = 0; e < NEXP; e += 2) {
      double2 p0 = *(const double2*)(part + base + e);
      double2 p1 = *(const double2*)(part + (size_t)T_TOK*NNE   + base + e);
      double2 p2 = *(const double2*)(part + (size_t)2*T_TOK*NNE + base + e);
      double2 p3 = *(const double2*)(part + (size_t)3*T_TOK*NNE + base + e);
      l[e]   = (((p0.x + p1.x) + p2.x) + p3.x) + lb[head*8 + e];
      l[e+1] = (((p0.y + p1.y) + p2.y) + p3.y) + lb[head*8 + e + 1];
    }
    int e1 = 0; double v1 = l[0];
    #pragma unroll
    for (int e = 1; e < NEXP; ++e) if (l[e] > v1) { v1 = l[e]; e1 = e; }
    int e2 = -1; double v2 = -1.0e300;
    #pragma unroll
    for (int e = 0; e < NEXP; ++e) if (e != e1 && l[e] > v2) { v2 = l[e]; e2 = e; }
    const double ed = exp(v2 - v1);
    const float w1 = (float)(1.0 / (1.0 + ed));
    const float w2 = (float)(ed / (1.0 + ed));
    const int b1 = head*NEXP + e1, b2 = head*NEXP + e2;

    wbuf[(size_t)(tok*NHEAD + head)*2 + 0] = w1;
    wbuf[(size_t)(tok*NHEAD + head)*2 + 1] = w2;

    const int p1i = atomicAdd(&lcnt[b1], 1);
    const int p2i = atomicAdd(&lcnt[b2], 1);
    __syncthreads();
    if (t < NNE) lbase[t] = atomicAdd(&counts[t], lcnt[t]);
    __syncthreads();
    lists[(size_t)b1*T_TOK + lbase[b1] + p1i] = tok*2;
    lists[(size_t)b2*T_TOK + lbase[b2] + p2i] = tok*2 + 1;
  }
}

// ---------------- out GEMM: BK=64 swizzled; bm-keyed XCD; slot-fusion in A ----------------
__global__ __launch_bounds__(256) void gemm_out(
    const unsigned short* __restrict__ ye, const unsigned short* __restrict__ B,
    const float* __restrict__ bias, float* __restrict__ C)
{
  const int N = DMODEL, K = DMODEL;
  __shared__ __align__(16) unsigned short As[128*64];   // 16 KB
  __shared__ __align__(16) unsigned short Bs[128*64];   // 16 KB
  const int t = threadIdx.x;
  const int lane = t & 63, w = t >> 6;
  const int bm = blockIdx.x << 7, bn = blockIdx.y << 7;
  const int wm = (w & 1) << 6, wn = (w >> 1) << 6;
  f32x4 acc[4][4];
  #pragma unroll
  for (int i = 0; i < 4; ++i)
    #pragma unroll
    for (int j = 0; j < 4; ++j)
      acc[i][j] = (f32x4){0.f, 0.f, 0.f, 0.f};

  const int srow = t >> 3;
  const int scol = ((t & 7) ^ (srow & 7)) << 3;
  const unsigned short* gB = B + (size_t)(bn + srow)*K + scol;
  const size_t row32 = (size_t)32*K;
  char* lB = (char*)Bs + t*16;
  const int arow = t >> 1;            // 0..127
  const int ah   = (t & 1) << 5;      // element offset 0/32 within 64-k step
  const int rlo = lane & 15;
  const int khi = (lane >> 4) << 4;

  int aRd[4][2], bRd[4][2];
  #pragma unroll
  for (int i = 0; i < 4; ++i) {
    const int ra = wm + i*16 + rlo;
    const int rb2 = wn + i*16 + rlo;
    #pragma unroll
    for (int ks = 0; ks < 2; ++ks) {
      aRd[i][ks] = ra*128 + ((ks*64 + khi) ^ ((ra & 7) << 4));
      bRd[i][ks] = rb2*128 + ((ks*64 + khi) ^ ((rb2 & 7) << 4));
    }
  }
  int aWr[4];
  #pragma unroll
  for (int j = 0; j < 4; ++j)
    aWr[j] = arow*128 + (((ah + 8*j)*2) ^ ((arow & 7) << 4));

  for (int k0 = 0; k0 < K; k0 += 64) {
    GLDS16(gB + k0,            lB);
    GLDS16(gB + row32 + k0,    lB + 4096);
    GLDS16(gB + 2*row32 + k0,  lB + 8192);
    GLDS16(gB + 3*row32 + k0,  lB + 12288);
    {
      const int head = k0 >> 7;
      const int inHead = (k0 & 127) + ah;
      const unsigned short* r0 = ye + (((size_t)(bm + arow)*NHEAD + head)*2)*DH + inHead;
      const unsigned short* r1 = r0 + DH;
      #pragma unroll
      for (int j = 0; j < 4; ++j) {
        const u16x8 a = *(const u16x8*)(r0 + 8*j);
        const u16x8 b = *(const u16x8*)(r1 + 8*j);
        u16x8 s;
        #pragma unroll
        for (int q = 0; q < 8; ++q) s[q] = f2bf(bf2f(a[q]) + bf2f(b[q]));
        *(u16x8*)((char*)As + aWr[j]) = s;
      }
    }
    __syncthreads();
    #pragma unroll
    for (int ks = 0; ks < 2; ++ks) {
      bf16x8 av[4], bv[4];
      #pragma unroll
      for (int i = 0; i < 4; ++i) {
        av[i] = *(const bf16x8*)((const char*)As + aRd[i][ks]);
        bv[i] = *(const bf16x8*)((const char*)Bs + bRd[i][ks]);
      }
      #pragma unroll
      for (int i = 0; i < 4; ++i)
        #pragma unroll
        for (int j = 0; j < 4; ++j)
          acc[i][j] = __builtin_amdgcn_mfma_f32_16x16x32_bf16(av[i], bv[j], acc[i][j], 0, 0, 0);
    }
    __syncthreads();
  }
  const int rq = (lane >> 4) << 2;
  #pragma unroll
  for (int j = 0; j < 4; ++j) {
    const int col = bn + wn + j*16 + rlo;
    const float bb = bias[col];
    #pragma unroll
    for (int i = 0; i < 4; ++i) {
      const int row0 = bm + wm + i*16 + rq;
      #pragma unroll
      for (int r = 0; r < 4; ++r)
        C[(size_t)(row0 + r)*N + col] = acc[i][j][r] + bb;
    }
  }
}

// ---------------- K3: fused expert FFN — dbuf weights via hA-space reuse ----------------
// LDS (bytes): [0,16K) hidS | [16K,32K) wIn0 | [32K,48K) wOut0 |
//              [48K,64K) wIn1 | [64K,80K) wOut1 ; hA staged at [48K,80K).
// A-fragments fully cached in regs (aReg[2][4], 32 VGPR) -> hA space becomes
// buffer 1. stage(c+1 -> other buf) issued BEFORE GEMM1: the __syncthreads
// vmcnt drain lands after GEMM1+gelu cover. 2 barriers/chunk. Bounds (512,4)
// proven: VGPR 60, no spill.
__global__ __launch_bounds__(512, 4) void ffn_mfma_kernel(
    const unsigned short* __restrict__ h_bf, const unsigned short* __restrict__ win_bf,
    const unsigned short* __restrict__ woutT_bf, const int* __restrict__ counts,
    const int* __restrict__ lists, const float* __restrict__ wbuf,
    unsigned short* __restrict__ ye_buf)
{
  const int ne = blockIdx.x;
  const int n  = ne >> 3;
  const int cnt = counts[ne];
  const int t0 = blockIdx.y << 7;
  if (t0 >= cnt) return;
  const int nt = min(128, cnt - t0);

  __shared__ __align__(16) unsigned short lds[40960];   // 80 KB
  char* const L = (char*)lds;

  const int t = threadIdx.x;
  const int lane = t & 63, w = t >> 6;
  const long lbase = (long)ne * T_TOK;

  // gather token rows of h into hA region [48K,80K)
  #pragma unroll
  for (int s = 0; s < 4; ++s) {
    const int o = s*8192 + t*16;
    const int row = o >> 8;
    const int c = (t & 15) ^ (row & 7);
    const int trow = t0 + row;
    const int ts = lists[lbase + (trow < cnt ? trow : t0)];
    const unsigned short* g = h_bf + (size_t)(ts >> 1)*DMODEL + n*DH + c*8;
    GLDS16(g, L + 49152 + o);
  }

  const unsigned short* winB  = win_bf  + (size_t)ne*DHID*DH;
  const unsigned short* woutB = woutT_bf + (size_t)ne*DH*DHID;

  const int wm = (w & 3) << 5;
  const int wf = (w >> 2) << 5;
  const int wd = (w >> 2) << 6;
  const int rlo = lane & 15;
  const int kq  = lane >> 4;

  int aAddr[2][4];
  #pragma unroll
  for (int i = 0; i < 2; ++i) {
    const int tr = wm + i*16 + rlo;
    #pragma unroll
    for (int ks = 0; ks < 4; ++ks)
      aAddr[i][ks] = tr*256 + ((ks*64 + kq*16) ^ ((tr & 7) << 4));
  }
  int bAddr[2][4];
  #pragma unroll
  for (int j = 0; j < 2; ++j) {
    const int fr = wf + j*16 + rlo;
    #pragma unroll
    for (int ks = 0; ks < 4; ++ks)
      bAddr[j][ks] = fr*256 + ((ks*64 + kq*16) ^ ((fr & 7) << 4));
  }
  int hWAddr[2][2];
  #pragma unroll
  for (int j = 0; j < 2; ++j)
    #pragma unroll
    for (int i = 0; i < 2; ++i) {
      const int tcol = wm + i*16 + rlo;
      const int fb   = wf + j*16 + kq*4;
      hWAddr[j][i] = tcol*128 + ((fb*2) ^ ((tcol & 7) << 4));
    }
  int a2Addr[2][2];
  #pragma unroll
  for (int i = 0; i < 2; ++i) {
    const int tr = wm + i*16 + rlo;
    #pragma unroll
    for (int ks = 0; ks < 2; ++ks)
      a2Addr[i][ks] = tr*128 + ((ks*64 + kq*16) ^ ((tr & 7) << 4));
  }
  int b2Addr[4][2];
  #pragma unroll
  for (int j = 0; j < 4; ++j) {
    const int dr = wd + j*16 + rlo;
    #pragma unroll
    for (int ks = 0; ks < 2; ++ks)
      b2Addr[j][ks] = dr*128 + ((ks*64 + kq*16) ^ ((dr & 7) << 4));
  }

  // pb = 0 (buf0) or 32768 (buf1)
  auto stage_win = [&](int fc, int pb) {
    #pragma unroll
    for (int s = 0; s < 2; ++s) {
      const int o = s*8192 + t*16;
      const int row = o >> 8;
      const int c = (t & 15) ^ (row & 7);
      GLDS16(winB + (size_t)(fc + row)*DH + c*8, L + 16384 + pb + o);
    }
  };
  auto stage_wout = [&](int fc, int pb) {
    #pragma unroll
    for (int s = 0; s < 2; ++s) {
      const int o = s*8192 + t*16;
      const int row = o >> 7;
      const int c = (t & 7) ^ (row & 7);
      GLDS16(woutB + (size_t)row*DHID + fc + c*8, L + 32768 + pb + o);
    }
  };

  f32x4 acc2[4][2];
  #pragma unroll
  for (int j = 0; j < 4; ++j)
    #pragma unroll
    for (int i = 0; i < 2; ++i)
      acc2[j][i] = (f32x4){0.f, 0.f, 0.f, 0.f};

  // prologue: hA + buf0 staged; cache ALL A-fragments; free hA space
  stage_win(0, 0);
  stage_wout(0, 0);
  __syncthreads();               // hA + buf0 visible
  bf16x8 aReg[2][4];
  #pragma unroll
  for (int i = 0; i < 2; ++i)
    #pragma unroll
    for (int ks = 0; ks < 4; ++ks)
      aReg[i][ks] = *(const bf16x8*)(L + 49152 + aAddr[i][ks]);
  __syncthreads();               // aReg reads complete -> hA space reusable

  #pragma unroll 1
  for (int c = 0; c < DHID/64; ++c) {
    const int fc = c << 6;
    const int pb = (c & 1) << 15;          // current buf: 0 / 32768
    if (c + 1 < DHID/64) {                 // stage next chunk into other buf
      const int qb = pb ^ 32768;
      stage_win(fc + 64, qb);
      stage_wout(fc + 64, qb);
    }
    // GEMM1: pure regs (A) + wIn[pb]
    f32x4 acc1[2][2];
    #pragma unroll
    for (int j = 0; j < 2; ++j)
      #pragma unroll
      for (int i = 0; i < 2; ++i)
        acc1[j][i] = (f32x4){0.f,0.f,0.f,0.f};
    __builtin_amdgcn_s_setprio(1);
    #pragma unroll
    for (int ks = 0; ks < 4; ++ks) {
      bf16x8 b[2];
      #pragma unroll
      for (int j = 0; j < 2; ++j)
        b[j] = *(const bf16x8*)(L + 16384 + pb + bAddr[j][ks]);
      #pragma unroll
      for (int j = 0; j < 2; ++j)
        #pragma unroll
        for (int i = 0; i < 2; ++i)
          acc1[j][i] = __builtin_amdgcn_mfma_f32_16x16x32_bf16(b[j], aReg[i][ks], acc1[j][i], 0, 0, 0);
    }
    __builtin_amdgcn_s_setprio(0);
    // gelu + packed b64 hid writes
    #pragma unroll
    for (int j = 0; j < 2; ++j)
      #pragma unroll
      for (int i = 0; i < 2; ++i) {
        const float g0 = gelu_f(acc1[j][i][0]);
        const float g1 = gelu_f(acc1[j][i][1]);
        const float g2 = gelu_f(acc1[j][i][2]);
        const float g3 = gelu_f(acc1[j][i][3]);
        const unsigned int lo = (unsigned int)f2bf(g0) | ((unsigned int)f2bf(g1) << 16);
        const unsigned int hi = (unsigned int)f2bf(g2) | ((unsigned int)f2bf(g3) << 16);
        *(uint2*)(L + hWAddr[j][i]) = make_uint2(lo, hi);
      }
    __syncthreads();   // BAR 1: staging(c+1) landed + hid visible (cover = GEMM1+gelu)

    // GEMM2: hidS + wOut[pb]
    __builtin_amdgcn_s_setprio(1);
    #pragma unroll
    for (int ks = 0; ks < 2; ++ks) {
      bf16x8 a[2], b[4];
      #pragma unroll
      for (int i = 0; i < 2; ++i)
        a[i] = *(const bf16x8*)(L + a2Addr[i][ks]);
      #pragma unroll
      for (int j = 0; j < 4; ++j)
        b[j] = *(const bf16x8*)(L + 32768 + pb + b2Addr[j][ks]);
      #pragma unroll
      for (int j = 0; j < 4; ++j)
        #pragma unroll
        for (int i = 0; i < 2; ++i)
          acc2[j][i] = __builtin_amdgcn_mfma_f32_16x16x32_bf16(b[j], a[i], acc2[j][i], 0, 0, 0);
    }
    __builtin_amdgcn_s_setprio(0);
    __syncthreads();   // BAR 2: hidS reads done -> next gelu may overwrite
  }

  // epilogue: gate-premultiplied packed b64 stores; lane holds 4 consecutive d
  #pragma unroll
  for (int i = 0; i < 2; ++i) {
    const int tr = wm + i*16 + rlo;
    if (tr < nt) {
      const int ts = lists[lbase + t0 + tr];
      const float gw = wbuf[(size_t)(ts >> 1)*NHEAD*2 + n*2 + (ts & 1)];
      unsigned short* dst = ye_buf +
          ((((size_t)(ts >> 1))*NHEAD + n)*2 + (ts & 1))*DH + wd + kq*4;
      #pragma unroll
      for (int j = 0; j < 4; ++j) {
        const unsigned int lo = (unsigned int)f2bf(gw*acc2[j][i][0]) |
                                ((unsigned int)f2bf(gw*acc2[j][i][1]) << 16);
        const unsigned int hi = (unsigned int)f2bf(gw*acc2[j][i][2]) |
                                ((unsigned int)f2bf(gw*acc2[j][i][3]) << 16);
        *(uint2*)(dst + j*16) = make_uint2(lo, hi);
      }
    }
  }
}

// ---------------- launch ----------------
extern "C" void kernel_launch(void* const* d_in, const int* in_sizes, int n_in,
                              void* d_out, int out_size, void* d_ws, size_t ws_size,
                              hipStream_t stream) {
  const float* x        = (const float*)d_in[0];
  const float* in_w     = (const float*)d_in[1];
  const float* in_b     = (const float*)d_in[2];
  const float* router_w = (const float*)d_in[3];
  const float* w_in     = (const float*)d_in[4];
  const float* w_out    = (const float*)d_in[5];
  const float* out_w    = (const float*)d_in[6];
  const float* out_b    = (const float*)d_in[7];
  float* out = (float*)d_out;

  size_t off = 0;
  char* base = (char*)d_ws;
  auto alloc = [&](size_t bytes) -> void* {
    void* p = base + off;
    off += (bytes + 255) & ~(size_t)255;
    return p;
  };
  unsigned short* h_bf    = (unsigned short*)alloc((size_t)T_TOK*DMODEL*2);
  unsigned short* x_bf    = (unsigned short*)alloc((size_t)T_TOK*DMODEL*2);
  unsigned short* inw_bf  = (unsigned short*)alloc((size_t)DMODEL*DMODEL*2);
  unsigned short* outw_bf = (unsigned short*)alloc((size_t)DMODEL*DMODEL*2);
  unsigned short* win_bf  = (unsigned short*)alloc((size_t)NNE*DHID*DH*2);
  unsigned short* woutT_bf= (unsigned short*)alloc((size_t)NNE*DH*DHID*2);
  unsigned short* ye_buf  = (unsigned short*)alloc((size_t)T_TOK*NHEAD*2*DH*2);
  float*  wbuf   = (float*) alloc((size_t)T_TOK*NHEAD*2*4);
  double* Rtp    = (double*)alloc((size_t)DMODEL*NNE*8);
  double* lb     = (double*)alloc(NNE*8);
  int*    counts = (int*)   alloc(NNE*4);
  int*    lists  = (int*)   alloc((size_t)NNE*T_TOK*4);
  double* part   = (double*)ye_buf;   // aliases ye_buf (router done before ffn)

  hipMemsetAsync(counts, 0, NNE*4, stream);

  // merged prep: transpose (w_out) | reff | cvt {x, in_w, out_w, w_in}
  prep_kernel<<<992, 256, 0, stream>>>(x, in_w, out_w, w_in, w_out, in_b, router_w,
                                       x_bf, inw_bf, outw_bf, win_bf,
                                       woutT_bf, Rtp, lb);

  // router partial logits (fp64, selection-exact)
  router_partial<<<4096, 64, 0, stream>>>(x, Rtp, part);

  // gemm1 (h = x @ in_w^T + in_b, bf16) + top-2 scatter, merged
  gemm1_top2<<<768, 256, 0, stream>>>(x_bf, inw_bf, in_b, h_bf,
                                      part, lb, counts, lists, wbuf);

  // expert FFN (top-2 sparse), dbuf weights
  ffn_mfma_kernel<<<dim3(NNE, T_TOK/128), 512, 0, stream>>>(
      h_bf, win_bf, woutT_bf, counts, lists, wbuf, ye_buf);

  // out = (ye0 + ye1) @ out_w^T + out_b  (fp32 out, BK=64 swizzled, bm-keyed XCD)
  gemm_out<<<dim3(T_TOK/128, DMODEL/128), 256, 0, stream>>>(
      ye_buf, outw_bf, out_b, out);
}

// Round 29
// 214.768 us; speedup vs baseline: 1.1078x; 1.0233x over previous
//
#include <hip/hip_runtime.h>
#include <hip/hip_bf16.h>
#include <cmath>

#define T_TOK 8192
#define DMODEL 1024
#define NHEAD 8
#define DH 128
#define NEXP 8
#define NNE 64      // NHEAD*NEXP
#define DHID 512

typedef __bf16 bf16x8 __attribute__((ext_vector_type(8)));
typedef float f32x4 __attribute__((ext_vector_type(4)));
typedef unsigned short u16x8 __attribute__((ext_vector_type(8)));

#define GLDS16(g, l) __builtin_amdgcn_global_load_lds( \
    (const __attribute__((address_space(1))) unsigned int*)(g), \
    (__attribute__((address_space(3))) unsigned int*)(l), 16, 0, 0)

static __device__ inline unsigned short f2bf(float f) {
  return __builtin_bit_cast(unsigned short, __float2bfloat16(f));
}
static __device__ inline float bf2f(unsigned short u) {
  unsigned int v = ((unsigned int)u) << 16;
  return __builtin_bit_cast(float, v);
}

// exact-accuracy fast gelu: Abramowitz-Stegun 7.1.26 erf (|eps|<=1.5e-7)
static __device__ inline float gelu_f(float v) {
  const float u = v * 0.70710678118654752f;
  const float s = fabsf(u);
  const float t = __builtin_amdgcn_rcpf(fmaf(0.3275911f, s, 1.0f));
  const float e = __expf(-s * s);
  float p = fmaf(1.061405429f, t, -1.453152027f);
  p = fmaf(p, t, 1.421413741f);
  p = fmaf(p, t, -0.284496736f);
  p = fmaf(p, t, 0.254829592f);
  p = p * t;
  const float erfs = fmaf(-p, e, 1.0f);
  const float erfv = copysignf(erfs, u);
  return 0.5f * v * (1.0f + erfv);
}

// ---------------- P0: merged prep ----------------
// blocks [0,64): w_out transpose (ne = bid)
// blocks [64,96): reff — block = (n, 4 j-slices via 4 waves); rbid==0 also
//                 zeroes counts (replaces the hipMemsetAsync stream node;
//                 stream-ordered 2 launches ahead of gemm1_top2's atomicAdd)
// blocks [96,992): fp32->bf16 convert of {x, in_w, out_w, w_in}, grid-stride
__global__ __launch_bounds__(256) void prep_kernel(
    const float* __restrict__ x, const float* __restrict__ in_w,
    const float* __restrict__ out_w, const float* __restrict__ w_in,
    const float* __restrict__ wout_src, const float* __restrict__ in_b,
    const float* __restrict__ router_w,
    unsigned short* __restrict__ x_bf, unsigned short* __restrict__ inw_bf,
    unsigned short* __restrict__ outw_bf, unsigned short* __restrict__ win_bf,
    unsigned short* __restrict__ woutT, double* __restrict__ Rtp,
    double* __restrict__ lb, int* __restrict__ counts)
{
  __shared__ __align__(16) char smem[17408];
  const int bid = blockIdx.x;
  const int tid = threadIdx.x;

  if (bid < NNE) {
    // ---- w_out [ne][f][d] fp32 -> woutT [ne][d][f] bf16 ----
    float (*ws)[DH+4] = (float(*)[DH+4])smem;
    const int ne = bid;
    const float* src = wout_src + (size_t)ne*DHID*DH;
    unsigned short* dst = woutT + (size_t)ne*DH*DHID;
    for (int fc = 0; fc < DHID; fc += 32) {
      __syncthreads();
      for (int i = tid; i < 32*DH; i += 256) {
        const int f = i >> 7, d = i & 127;
        ws[f][d] = src[(size_t)(fc+f)*DH + d];
      }
      __syncthreads();
      for (int i = tid; i < 32*DH; i += 256) {
        const int d = i >> 5, f = i & 31;
        dst[(size_t)d*DHID + fc + f] = f2bf(ws[f][d]);
      }
    }
  } else if (bid < NNE + 32) {
    // ---- reff: Rtp[k/2][ne][2] fp64 ----
    double (*rw)[DH] = (double(*)[DH])smem;
    const int rbid = bid - NNE;
    if (rbid == 0 && tid < NNE) counts[tid] = 0;   // replaces memset launch
    const int n  = rbid >> 2;
    const int w  = tid >> 6;
    const int lane = tid & 63;
    const int js = ((rbid & 3) << 2) + w;       // 0..15
    const int j = js*64 + lane;
    for (int i = tid; i < 8*DH; i += 256)
      rw[i >> 7][i & 127] = (double)router_w[(size_t)(n*8 + (i >> 7))*DH + (i & 127)];
    __syncthreads();
    double acc[8];
    #pragma unroll
    for (int e = 0; e < 8; ++e) acc[e] = 0.0;
    const float* wp = in_w + (size_t)(n*DH)*DMODEL + j;
    #pragma unroll 8
    for (int d = 0; d < DH; ++d) {
      const double wv = (double)wp[(size_t)d*DMODEL];
      #pragma unroll
      for (int e = 0; e < 8; ++e) acc[e] += wv * rw[e][d];
    }
    #pragma unroll
    for (int e = 0; e < 8; ++e)
      Rtp[(size_t)(j >> 1)*128 + (n*8 + e)*2 + (j & 1)] = acc[e];
    if (js == 0 && lane < 8) {
      double a = 0.0;
      for (int d = 0; d < DH; ++d) a += (double)in_b[n*DH + d] * rw[lane][d];
      lb[n*8 + lane] = a;
    }
  } else {
    // ---- fp32 -> bf16 convert, grid-stride over 4 buffers ----
    const int N0 = T_TOK*DMODEL/8;
    const int N1 = N0 + DMODEL*DMODEL/8;
    const int N2 = N1 + DMODEL*DMODEL/8;
    const int N3 = N2 + NNE*DHID*DH/8;
    const int nblk = 992 - 96;
    for (int i = (bid - 96)*256 + tid; i < N3; i += nblk*256) {
      const float* s; unsigned short* d; int o;
      if (i < N0)      { s = x;     d = x_bf;    o = i; }
      else if (i < N1) { s = in_w;  d = inw_bf;  o = i - N0; }
      else if (i < N2) { s = out_w; d = outw_bf; o = i - N1; }
      else             { s = w_in;  d = win_bf;  o = i - N2; }
      const float4 a = *((const float4*)s + (size_t)o*2);
      const float4 b = *((const float4*)s + (size_t)o*2 + 1);
      u16x8 v;
      v[0]=f2bf(a.x); v[1]=f2bf(a.y); v[2]=f2bf(a.z); v[3]=f2bf(a.w);
      v[4]=f2bf(b.x); v[5]=f2bf(b.y); v[6]=f2bf(b.z); v[7]=f2bf(b.w);
      *((u16x8*)d + o) = v;
    }
  }
}

// ---------------- K1a: fp64 partial logits (block-uniform x -> s_load) ----------------
__global__ __launch_bounds__(64) void router_partial(
    const float* __restrict__ x, const double* __restrict__ Rtp,
    double* __restrict__ part)
{
  const int bid = blockIdx.x;
  const int s  = bid & 3;
  const int tg = bid >> 2;
  const int t0 = tg << 3;
  const int k0 = s << 8;
  const int lane = threadIdx.x;          // ne

  double acc[8];
  #pragma unroll
  for (int t = 0; t < 8; ++t) acc[t] = 0.0;

  const float*  xb = x + (size_t)t0*DMODEL + k0;
  const double* rb = Rtp + (size_t)(k0 >> 1)*128 + lane*2;

  #pragma unroll 2
  for (int kc = 0; kc < 256; kc += 8) {
    const double* r = rb + (size_t)(kc >> 1)*128;
    const double2 r0 = *(const double2*)(r);
    const double2 r1 = *(const double2*)(r + 128);
    const double2 r2 = *(const double2*)(r + 256);
    const double2 r3 = *(const double2*)(r + 384);
    #pragma unroll
    for (int t = 0; t < 8; ++t) {
      const float4 xa = *(const float4*)(xb + (size_t)t*DMODEL + kc);
      const float4 xc = *(const float4*)(xb + (size_t)t*DMODEL + kc + 4);
      acc[t] += (double)xa.x * r0.x;
      acc[t] += (double)xa.y * r0.y;
      acc[t] += (double)xa.z * r1.x;
      acc[t] += (double)xa.w * r1.y;
      acc[t] += (double)xc.x * r2.x;
      acc[t] += (double)xc.y * r2.y;
      acc[t] += (double)xc.z * r3.x;
      acc[t] += (double)xc.w * r3.y;
    }
  }
  #pragma unroll
  for (int t = 0; t < 8; ++t)
    part[((size_t)s*T_TOK + t0 + t)*NNE + lane] = acc[t];
}

// ---------------- K2: gemm1 (blocks 0..511) + top-2 scatter (blocks 512..767) ----------------
// gemm branch dominates the VGPR union (top2 ~40 VGPR) -> gemm occupancy
// unaffected. bm = bid&63 keeps XCD = bm%8 (A-panel L2 locality).
__global__ __launch_bounds__(256) void gemm1_top2(
    const unsigned short* __restrict__ A, const unsigned short* __restrict__ B,
    const float* __restrict__ bias, unsigned short* __restrict__ C,
    const double* __restrict__ part, const double* __restrict__ lb,
    int* __restrict__ counts, int* __restrict__ lists, float* __restrict__ wbuf)
{
  const int bid = blockIdx.x;
  const int t = threadIdx.x;

  if (bid < 512) {
    const int N = DMODEL, K = DMODEL;
    __shared__ __align__(16) unsigned short As[128*64];   // 16 KB
    __shared__ __align__(16) unsigned short Bs[128*64];   // 16 KB
    const int lane = t & 63, w = t >> 6;
    const int bm = (bid & 63) << 7, bn = (bid >> 6) << 7;
    const int wm = (w & 1) << 6, wn = (w >> 1) << 6;
    f32x4 acc[4][4];
    #pragma unroll
    for (int i = 0; i < 4; ++i)
      #pragma unroll
      for (int j = 0; j < 4; ++j)
        acc[i][j] = (f32x4){0.f, 0.f, 0.f, 0.f};

    const int srow = t >> 3;                        // 0..31
    const int scol = ((t & 7) ^ (srow & 7)) << 3;   // inverse-swizzled source col
    const unsigned short* gA = A + (size_t)(bm + srow)*K + scol;
    const unsigned short* gB = B + (size_t)(bn + srow)*K + scol;
    const size_t row32 = (size_t)32*K;
    char* lA = (char*)As + t*16;
    char* lB = (char*)Bs + t*16;
    const int rlo = lane & 15;
    const int khi = (lane >> 4) << 4;

    int aRd[4][2], bRd[4][2];
    #pragma unroll
    for (int i = 0; i < 4; ++i) {
      const int ra = wm + i*16 + rlo;
      const int rb2 = wn + i*16 + rlo;
      #pragma unroll
      for (int ks = 0; ks < 2; ++ks) {
        aRd[i][ks] = ra*128 + ((ks*64 + khi) ^ ((ra & 7) << 4));
        bRd[i][ks] = rb2*128 + ((ks*64 + khi) ^ ((rb2 & 7) << 4));
      }
    }

    for (int k0 = 0; k0 < K; k0 += 64) {
      GLDS16(gA + k0,            lA);
      GLDS16(gA + row32 + k0,    lA + 4096);
      GLDS16(gA + 2*row32 + k0,  lA + 8192);
      GLDS16(gA + 3*row32 + k0,  lA + 12288);
      GLDS16(gB + k0,            lB);
      GLDS16(gB + row32 + k0,    lB + 4096);
      GLDS16(gB + 2*row32 + k0,  lB + 8192);
      GLDS16(gB + 3*row32 + k0,  lB + 12288);
      __syncthreads();
      #pragma unroll
      for (int ks = 0; ks < 2; ++ks) {
        bf16x8 av[4], bv[4];
        #pragma unroll
        for (int i = 0; i < 4; ++i) {
          av[i] = *(const bf16x8*)((const char*)As + aRd[i][ks]);
          bv[i] = *(const bf16x8*)((const char*)Bs + bRd[i][ks]);
        }
        #pragma unroll
        for (int i = 0; i < 4; ++i)
          #pragma unroll
          for (int j = 0; j < 4; ++j)
            acc[i][j] = __builtin_amdgcn_mfma_f32_16x16x32_bf16(av[i], bv[j], acc[i][j], 0, 0, 0);
      }
      __syncthreads();
    }
    const int rq = (lane >> 4) << 2;
    #pragma unroll
    for (int j = 0; j < 4; ++j) {
      const int col = bn + wn + j*16 + rlo;
      const float bb = bias[col];
      #pragma unroll
      for (int i = 0; i < 4; ++i) {
        const int row0 = bm + wm + i*16 + rq;
        #pragma unroll
        for (int r = 0; r < 4; ++r)
          C[(size_t)(row0 + r)*N + col] = f2bf(acc[i][j][r] + bb);
      }
    }
  } else {
    // ---- top-2 + softmax + hierarchical bucket scatter ----
    __shared__ int lcnt[NNE];
    __shared__ int lbase[NNE];
    const int u = (bid - 512)*256 + t;   // (tok, head)
    const int tok = u >> 3;
    const int head = u & 7;
    if (t < NNE) lcnt[t] = 0;
    __syncthreads();

    const size_t base = (size_t)tok*NNE + head*8;
    double l[NEXP];
    #pragma unroll
    for (int e = 0; e < NEXP; e += 2) {
      double2 p0 = *(const double2*)(part + base + e);
      double2 p1 = *(const double2*)(part + (size_t)T_TOK*NNE   + base + e);
      double2 p2 = *(const double2*)(part + (size_t)2*T_TOK*NNE + base + e);
      double2 p3 = *(const double2*)(part + (size_t)3*T_TOK*NNE + base + e);
      l[e]   = (((p0.x + p1.x) + p2.x) + p3.x) + lb[head*8 + e];
      l[e+1] = (((p0.y + p1.y) + p2.y) + p3.y) + lb[head*8 + e + 1];
    }
    int e1 = 0; double v1 = l[0];
    #pragma unroll
    for (int e = 1; e < NEXP; ++e) if (l[e] > v1) { v1 = l[e]; e1 = e; }
    int e2 = -1; double v2 = -1.0e300;
    #pragma unroll
    for (int e = 0; e < NEXP; ++e) if (e != e1 && l[e] > v2) { v2 = l[e]; e2 = e; }
    const double ed = exp(v2 - v1);
    const float w1 = (float)(1.0 / (1.0 + ed));
    const float w2 = (float)(ed / (1.0 + ed));
    const int b1 = head*NEXP + e1, b2 = head*NEXP + e2;

    wbuf[(size_t)(tok*NHEAD + head)*2 + 0] = w1;
    wbuf[(size_t)(tok*NHEAD + head)*2 + 1] = w2;

    const int p1i = atomicAdd(&lcnt[b1], 1);
    const int p2i = atomicAdd(&lcnt[b2], 1);
    __syncthreads();
    if (t < NNE) lbase[t] = atomicAdd(&counts[t], lcnt[t]);
    __syncthreads();
    lists[(size_t)b1*T_TOK + lbase[b1] + p1i] = tok*2;
    lists[(size_t)b2*T_TOK + lbase[b2] + p2i] = tok*2 + 1;
  }
}

// ---------------- out GEMM: BK=64 swizzled; bm-keyed XCD; slot-fusion in A ----------------
__global__ __launch_bounds__(256) void gemm_out(
    const unsigned short* __restrict__ ye, const unsigned short* __restrict__ B,
    const float* __restrict__ bias, float* __restrict__ C)
{
  const int N = DMODEL, K = DMODEL;
  __shared__ __align__(16) unsigned short As[128*64];   // 16 KB
  __shared__ __align__(16) unsigned short Bs[128*64];   // 16 KB
  const int t = threadIdx.x;
  const int lane = t & 63, w = t >> 6;
  const int bm = blockIdx.x << 7, bn = blockIdx.y << 7;
  const int wm = (w & 1) << 6, wn = (w >> 1) << 6;
  f32x4 acc[4][4];
  #pragma unroll
  for (int i = 0; i < 4; ++i)
    #pragma unroll
    for (int j = 0; j < 4; ++j)
      acc[i][j] = (f32x4){0.f, 0.f, 0.f, 0.f};

  const int srow = t >> 3;
  const int scol = ((t & 7) ^ (srow & 7)) << 3;
  const unsigned short* gB = B + (size_t)(bn + srow)*K + scol;
  const size_t row32 = (size_t)32*K;
  char* lB = (char*)Bs + t*16;
  const int arow = t >> 1;            // 0..127
  const int ah   = (t & 1) << 5;      // element offset 0/32 within 64-k step
  const int rlo = lane & 15;
  const int khi = (lane >> 4) << 4;

  int aRd[4][2], bRd[4][2];
  #pragma unroll
  for (int i = 0; i < 4; ++i) {
    const int ra = wm + i*16 + rlo;
    const int rb2 = wn + i*16 + rlo;
    #pragma unroll
    for (int ks = 0; ks < 2; ++ks) {
      aRd[i][ks] = ra*128 + ((ks*64 + khi) ^ ((ra & 7) << 4));
      bRd[i][ks] = rb2*128 + ((ks*64 + khi) ^ ((rb2 & 7) << 4));
    }
  }
  int aWr[4];
  #pragma unroll
  for (int j = 0; j < 4; ++j)
    aWr[j] = arow*128 + (((ah + 8*j)*2) ^ ((arow & 7) << 4));

  for (int k0 = 0; k0 < K; k0 += 64) {
    GLDS16(gB + k0,            lB);
    GLDS16(gB + row32 + k0,    lB + 4096);
    GLDS16(gB + 2*row32 + k0,  lB + 8192);
    GLDS16(gB + 3*row32 + k0,  lB + 12288);
    {
      const int head = k0 >> 7;
      const int inHead = (k0 & 127) + ah;
      const unsigned short* r0 = ye + (((size_t)(bm + arow)*NHEAD + head)*2)*DH + inHead;
      const unsigned short* r1 = r0 + DH;
      #pragma unroll
      for (int j = 0; j < 4; ++j) {
        const u16x8 a = *(const u16x8*)(r0 + 8*j);
        const u16x8 b = *(const u16x8*)(r1 + 8*j);
        u16x8 s;
        #pragma unroll
        for (int q = 0; q < 8; ++q) s[q] = f2bf(bf2f(a[q]) + bf2f(b[q]));
        *(u16x8*)((char*)As + aWr[j]) = s;
      }
    }
    __syncthreads();
    #pragma unroll
    for (int ks = 0; ks < 2; ++ks) {
      bf16x8 av[4], bv[4];
      #pragma unroll
      for (int i = 0; i < 4; ++i) {
        av[i] = *(const bf16x8*)((const char*)As + aRd[i][ks]);
        bv[i] = *(const bf16x8*)((const char*)Bs + bRd[i][ks]);
      }
      #pragma unroll
      for (int i = 0; i < 4; ++i)
        #pragma unroll
        for (int j = 0; j < 4; ++j)
          acc[i][j] = __builtin_amdgcn_mfma_f32_16x16x32_bf16(av[i], bv[j], acc[i][j], 0, 0, 0);
    }
    __syncthreads();
  }
  const int rq = (lane >> 4) << 2;
  #pragma unroll
  for (int j = 0; j < 4; ++j) {
    const int col = bn + wn + j*16 + rlo;
    const float bb = bias[col];
    #pragma unroll
    for (int i = 0; i < 4; ++i) {
      const int row0 = bm + wm + i*16 + rq;
      #pragma unroll
      for (int r = 0; r < 4; ++r)
        C[(size_t)(row0 + r)*N + col] = acc[i][j][r] + bb;
    }
  }
}

// ---------------- K3: fused expert FFN — dbuf weights via hA-space reuse ----------------
// LDS (bytes): [0,16K) hidS | [16K,32K) wIn0 | [32K,48K) wOut0 |
//              [48K,64K) wIn1 | [64K,80K) wOut1 ; hA staged at [48K,80K).
// A-fragments fully cached in regs (aReg[2][4], 32 VGPR) -> hA space becomes
// buffer 1. stage(c+1 -> other buf) issued BEFORE GEMM1: the __syncthreads
// vmcnt drain lands after GEMM1+gelu cover. 2 barriers/chunk. Bounds (512,4)
// proven: VGPR 60, no spill.
__global__ __launch_bounds__(512, 4) void ffn_mfma_kernel(
    const unsigned short* __restrict__ h_bf, const unsigned short* __restrict__ win_bf,
    const unsigned short* __restrict__ woutT_bf, const int* __restrict__ counts,
    const int* __restrict__ lists, const float* __restrict__ wbuf,
    unsigned short* __restrict__ ye_buf)
{
  const int ne = blockIdx.x;
  const int n  = ne >> 3;
  const int cnt = counts[ne];
  const int t0 = blockIdx.y << 7;
  if (t0 >= cnt) return;
  const int nt = min(128, cnt - t0);

  __shared__ __align__(16) unsigned short lds[40960];   // 80 KB
  char* const L = (char*)lds;

  const int t = threadIdx.x;
  const int lane = t & 63, w = t >> 6;
  const long lbase = (long)ne * T_TOK;

  // gather token rows of h into hA region [48K,80K)
  #pragma unroll
  for (int s = 0; s < 4; ++s) {
    const int o = s*8192 + t*16;
    const int row = o >> 8;
    const int c = (t & 15) ^ (row & 7);
    const int trow = t0 + row;
    const int ts = lists[lbase + (trow < cnt ? trow : t0)];
    const unsigned short* g = h_bf + (size_t)(ts >> 1)*DMODEL + n*DH + c*8;
    GLDS16(g, L + 49152 + o);
  }

  const unsigned short* winB  = win_bf  + (size_t)ne*DHID*DH;
  const unsigned short* woutB = woutT_bf + (size_t)ne*DH*DHID;

  const int wm = (w & 3) << 5;
  const int wf = (w >> 2) << 5;
  const int wd = (w >> 2) << 6;
  const int rlo = lane & 15;
  const int kq  = lane >> 4;

  int aAddr[2][4];
  #pragma unroll
  for (int i = 0; i < 2; ++i) {
    const int tr = wm + i*16 + rlo;
    #pragma unroll
    for (int ks = 0; ks < 4; ++ks)
      aAddr[i][ks] = tr*256 + ((ks*64 + kq*16) ^ ((tr & 7) << 4));
  }
  int bAddr[2][4];
  #pragma unroll
  for (int j = 0; j < 2; ++j) {
    const int fr = wf + j*16 + rlo;
    #pragma unroll
    for (int ks = 0; ks < 4; ++ks)
      bAddr[j][ks] = fr*256 + ((ks*64 + kq*16) ^ ((fr & 7) << 4));
  }
  int hWAddr[2][2];
  #pragma unroll
  for (int j = 0; j < 2; ++j)
    #pragma unroll
    for (int i = 0; i < 2; ++i) {
      const int tcol = wm + i*16 + rlo;
      const int fb   = wf + j*16 + kq*4;
      hWAddr[j][i] = tcol*128 + ((fb*2) ^ ((tcol & 7) << 4));
    }
  int a2Addr[2][2];
  #pragma unroll
  for (int i = 0; i < 2; ++i) {
    const int tr = wm + i*16 + rlo;
    #pragma unroll
    for (int ks = 0; ks < 2; ++ks)
      a2Addr[i][ks] = tr*128 + ((ks*64 + kq*16) ^ ((tr & 7) << 4));
  }
  int b2Addr[4][2];
  #pragma unroll
  for (int j = 0; j < 4; ++j) {
    const int dr = wd + j*16 + rlo;
    #pragma unroll
    for (int ks = 0; ks < 2; ++ks)
      b2Addr[j][ks] = dr*128 + ((ks*64 + kq*16) ^ ((dr & 7) << 4));
  }

  // pb = 0 (buf0) or 32768 (buf1)
  auto stage_win = [&](int fc, int pb) {
    #pragma unroll
    for (int s = 0; s < 2; ++s) {
      const int o = s*8192 + t*16;
      const int row = o >> 8;
      const int c = (t & 15) ^ (row & 7);
      GLDS16(winB + (size_t)(fc + row)*DH + c*8, L + 16384 + pb + o);
    }
  };
  auto stage_wout = [&](int fc, int pb) {
    #pragma unroll
    for (int s = 0; s < 2; ++s) {
      const int o = s*8192 + t*16;
      const int row = o >> 7;
      const int c = (t & 7) ^ (row & 7);
      GLDS16(woutB + (size_t)row*DHID + fc + c*8, L + 32768 + pb + o);
    }
  };

  f32x4 acc2[4][2];
  #pragma unroll
  for (int j = 0; j < 4; ++j)
    #pragma unroll
    for (int i = 0; i < 2; ++i)
      acc2[j][i] = (f32x4){0.f, 0.f, 0.f, 0.f};

  // prologue: hA + buf0 staged; cache ALL A-fragments; free hA space
  stage_win(0, 0);
  stage_wout(0, 0);
  __syncthreads();               // hA + buf0 visible
  bf16x8 aReg[2][4];
  #pragma unroll
  for (int i = 0; i < 2; ++i)
    #pragma unroll
    for (int ks = 0; ks < 4; ++ks)
      aReg[i][ks] = *(const bf16x8*)(L + 49152 + aAddr[i][ks]);
  __syncthreads();               // aReg reads complete -> hA space reusable

  #pragma unroll 1
  for (int c = 0; c < DHID/64; ++c) {
    const int fc = c << 6;
    const int pb = (c & 1) << 15;          // current buf: 0 / 32768
    if (c + 1 < DHID/64) {                 // stage next chunk into other buf
      const int qb = pb ^ 32768;
      stage_win(fc + 64, qb);
      stage_wout(fc + 64, qb);
    }
    // GEMM1: pure regs (A) + wIn[pb]
    f32x4 acc1[2][2];
    #pragma unroll
    for (int j = 0; j < 2; ++j)
      #pragma unroll
      for (int i = 0; i < 2; ++i)
        acc1[j][i] = (f32x4){0.f,0.f,0.f,0.f};
    __builtin_amdgcn_s_setprio(1);
    #pragma unroll
    for (int ks = 0; ks < 4; ++ks) {
      bf16x8 b[2];
      #pragma unroll
      for (int j = 0; j < 2; ++j)
        b[j] = *(const bf16x8*)(L + 16384 + pb + bAddr[j][ks]);
      #pragma unroll
      for (int j = 0; j < 2; ++j)
        #pragma unroll
        for (int i = 0; i < 2; ++i)
          acc1[j][i] = __builtin_amdgcn_mfma_f32_16x16x32_bf16(b[j], aReg[i][ks], acc1[j][i], 0, 0, 0);
    }
    __builtin_amdgcn_s_setprio(0);
    // gelu + packed b64 hid writes
    #pragma unroll
    for (int j = 0; j < 2; ++j)
      #pragma unroll
      for (int i = 0; i < 2; ++i) {
        const float g0 = gelu_f(acc1[j][i][0]);
        const float g1 = gelu_f(acc1[j][i][1]);
        const float g2 = gelu_f(acc1[j][i][2]);
        const float g3 = gelu_f(acc1[j][i][3]);
        const unsigned int lo = (unsigned int)f2bf(g0) | ((unsigned int)f2bf(g1) << 16);
        const unsigned int hi = (unsigned int)f2bf(g2) | ((unsigned int)f2bf(g3) << 16);
        *(uint2*)(L + hWAddr[j][i]) = make_uint2(lo, hi);
      }
    __syncthreads();   // BAR 1: staging(c+1) landed + hid visible (cover = GEMM1+gelu)

    // GEMM2: hidS + wOut[pb]
    __builtin_amdgcn_s_setprio(1);
    #pragma unroll
    for (int ks = 0; ks < 2; ++ks) {
      bf16x8 a[2], b[4];
      #pragma unroll
      for (int i = 0; i < 2; ++i)
        a[i] = *(const bf16x8*)(L + a2Addr[i][ks]);
      #pragma unroll
      for (int j = 0; j < 4; ++j)
        b[j] = *(const bf16x8*)(L + 32768 + pb + b2Addr[j][ks]);
      #pragma unroll
      for (int j = 0; j < 4; ++j)
        #pragma unroll
        for (int i = 0; i < 2; ++i)
          acc2[j][i] = __builtin_amdgcn_mfma_f32_16x16x32_bf16(b[j], a[i], acc2[j][i], 0, 0, 0);
    }
    __builtin_amdgcn_s_setprio(0);
    __syncthreads();   // BAR 2: hidS reads done -> next gelu may overwrite
  }

  // epilogue: gate-premultiplied packed b64 stores; lane holds 4 consecutive d
  #pragma unroll
  for (int i = 0; i < 2; ++i) {
    const int tr = wm + i*16 + rlo;
    if (tr < nt) {
      const int ts = lists[lbase + t0 + tr];
      const float gw = wbuf[(size_t)(ts >> 1)*NHEAD*2 + n*2 + (ts & 1)];
      unsigned short* dst = ye_buf +
          ((((size_t)(ts >> 1))*NHEAD + n)*2 + (ts & 1))*DH + wd + kq*4;
      #pragma unroll
      for (int j = 0; j < 4; ++j) {
        const unsigned int lo = (unsigned int)f2bf(gw*acc2[j][i][0]) |
                                ((unsigned int)f2bf(gw*acc2[j][i][1]) << 16);
        const unsigned int hi = (unsigned int)f2bf(gw*acc2[j][i][2]) |
                                ((unsigned int)f2bf(gw*acc2[j][i][3]) << 16);
        *(uint2*)(dst + j*16) = make_uint2(lo, hi);
      }
    }
  }
}

// ---------------- launch ----------------
extern "C" void kernel_launch(void* const* d_in, const int* in_sizes, int n_in,
                              void* d_out, int out_size, void* d_ws, size_t ws_size,
                              hipStream_t stream) {
  const float* x        = (const float*)d_in[0];
  const float* in_w     = (const float*)d_in[1];
  const float* in_b     = (const float*)d_in[2];
  const float* router_w = (const float*)d_in[3];
  const float* w_in     = (const float*)d_in[4];
  const float* w_out    = (const float*)d_in[5];
  const float* out_w    = (const float*)d_in[6];
  const float* out_b    = (const float*)d_in[7];
  float* out = (float*)d_out;

  size_t off = 0;
  char* base = (char*)d_ws;
  auto alloc = [&](size_t bytes) -> void* {
    void* p = base + off;
    off += (bytes + 255) & ~(size_t)255;
    return p;
  };
  unsigned short* h_bf    = (unsigned short*)alloc((size_t)T_TOK*DMODEL*2);
  unsigned short* x_bf    = (unsigned short*)alloc((size_t)T_TOK*DMODEL*2);
  unsigned short* inw_bf  = (unsigned short*)alloc((size_t)DMODEL*DMODEL*2);
  unsigned short* outw_bf = (unsigned short*)alloc((size_t)DMODEL*DMODEL*2);
  unsigned short* win_bf  = (unsigned short*)alloc((size_t)NNE*DHID*DH*2);
  unsigned short* woutT_bf= (unsigned short*)alloc((size_t)NNE*DH*DHID*2);
  unsigned short* ye_buf  = (unsigned short*)alloc((size_t)T_TOK*NHEAD*2*DH*2);
  float*  wbuf   = (float*) alloc((size_t)T_TOK*NHEAD*2*4);
  double* Rtp    = (double*)alloc((size_t)DMODEL*NNE*8);
  double* lb     = (double*)alloc(NNE*8);
  int*    counts = (int*)   alloc(NNE*4);
  int*    lists  = (int*)   alloc((size_t)NNE*T_TOK*4);
  double* part   = (double*)ye_buf;   // aliases ye_buf (router done before ffn)

  // merged prep: transpose (w_out) | reff (+counts zero) | cvt {x, in_w, out_w, w_in}
  prep_kernel<<<992, 256, 0, stream>>>(x, in_w, out_w, w_in, w_out, in_b, router_w,
                                       x_bf, inw_bf, outw_bf, win_bf,
                                       woutT_bf, Rtp, lb, counts);

  // router partial logits (fp64, selection-exact)
  router_partial<<<4096, 64, 0, stream>>>(x, Rtp, part);

  // gemm1 (h = x @ in_w^T + in_b, bf16) + top-2 scatter, merged
  gemm1_top2<<<768, 256, 0, stream>>>(x_bf, inw_bf, in_b, h_bf,
                                      part, lb, counts, lists, wbuf);

  // expert FFN (top-2 sparse), dbuf weights
  ffn_mfma_kernel<<<dim3(NNE, T_TOK/128), 512, 0, stream>>>(
      h_bf, win_bf, woutT_bf, counts, lists, wbuf, ye_buf);

  // out = (ye0 + ye1) @ out_w^T + out_b  (fp32 out, BK=64 swizzled, bm-keyed XCD)
  gemm_out<<<dim3(T_TOK/128, DMODEL/128), 256, 0, stream>>>(
      ye_buf, outw_bf, out_b, out);
}